// Round 1
// baseline (521.807 us; speedup 1.0000x reference)
//
#include <hip/hip_runtime.h>

#define NTOT 262144   // B*L
#define NLAY 8
#define TOUT 240      // output nodes per block in k_stack (256 LDS nodes - 2*8 halo)

__device__ __forceinline__ float silu_f(float x) {
    return x * (1.0f / (1.0f + __expf(-x)));
}

// ---------------- Kernel 1: encode  (mask/pos -> h0, pos0) ----------------
// 64 nodes per block, 256 threads. Stage inputs coalesced into LDS, then 64
// threads compute one node each (memory-bound kernel; idle waves don't issue).
__global__ __launch_bounds__(256) void k_encode(
    const float* __restrict__ ap, const float* __restrict__ amask,
    const float* __restrict__ embW, const float* __restrict__ embB,
    const float* __restrict__ peW1, const float* __restrict__ peB1,
    const float* __restrict__ peW2, const float* __restrict__ peB2,
    float* __restrict__ h0, float* __restrict__ pos0)
{
    __shared__ alignas(16) float sM[64 * 37];
    __shared__ alignas(16) float sA[64 * 111];
    const int tid = threadIdx.x;
    const long nb = (long)blockIdx.x * 64;

    const float4* gm = (const float4*)(amask + nb * 37);
    float4* sm4 = (float4*)sM;
    #pragma unroll 1
    for (int i = tid; i < 64 * 37 / 4; i += 256) sm4[i] = gm[i];
    const float4* ga = (const float4*)(ap + nb * 111);
    float4* sa4 = (float4*)sA;
    #pragma unroll 1
    for (int i = tid; i < 64 * 111 / 4; i += 256) sa4[i] = ga[i];
    __syncthreads();

    if (tid < 64) {
        const float* mrow = sM + tid * 37;
        const float* arow = sA + tid * 111;
        float hacc[8];
        #pragma unroll
        for (int j = 0; j < 8; ++j) hacc[j] = embB[j];
        float ps0 = 0.f, ps1 = 0.f, ps2 = 0.f, msum = 0.f;
        #pragma unroll 1
        for (int k = 0; k < 37; ++k) {
            float mv = mrow[k];
            msum += mv;
            #pragma unroll
            for (int j = 0; j < 8; ++j) hacc[j] += mv * embW[k * 8 + j];
            ps0 += mv * arow[k * 3 + 0];
            ps1 += mv * arow[k * 3 + 1];
            ps2 += mv * arow[k * 3 + 2];
        }
        float inv = 1.0f / (msum + 1e-8f);
        float mp0 = ps0 * inv, mp1 = ps1 * inv, mp2 = ps2 * inv;
        float q[8];
        #pragma unroll
        for (int j = 0; j < 8; ++j) {
            float a = peB1[j];
            a += mp0 * peW1[0 * 8 + j];
            a += mp1 * peW1[1 * 8 + j];
            a += mp2 * peW1[2 * 8 + j];
            q[j] = silu_f(a);
        }
        #pragma unroll
        for (int j = 0; j < 8; ++j) {
            float a = peB2[j];
            #pragma unroll
            for (int r = 0; r < 8; ++r) a += q[r] * peW2[r * 8 + j];
            hacc[j] += a;
        }
        const long g = nb + tid;
        float4* hd = (float4*)(h0 + g * 8);
        hd[0] = make_float4(hacc[0], hacc[1], hacc[2], hacc[3]);
        hd[1] = make_float4(hacc[4], hacc[5], hacc[6], hacc[7]);
        ((float4*)pos0)[g] = make_float4(mp0, mp1, mp2, 0.f);
    }
}

// ---------------- Kernel 2: fused 8-layer SE3 stack + mid latent ----------
// 256 LDS nodes per block (240 outputs, halo 8 each side). Compute is
// unconditional (uniform control flow -> scalar weight loads); only LDS/global
// stores are guarded by the shrinking validity window.
__global__ __launch_bounds__(256) void k_stack(
    const float* __restrict__ h0, const float* __restrict__ pos0,
    float* __restrict__ hfin,
    const float* __restrict__ ceW1, const float* __restrict__ ceB1,
    const float* __restrict__ ceW2, const float* __restrict__ ceB2,
    const float* __restrict__ cpW1, const float* __restrict__ cpB1,
    const float* __restrict__ cpW2,
    const float* __restrict__ cnW1, const float* __restrict__ cnB1,
    const float* __restrict__ cnW2, const float* __restrict__ cnB2,
    const float* __restrict__ tW1, const float* __restrict__ tB1,
    const float* __restrict__ tW2, const float* __restrict__ tB2,
    const float* __restrict__ fW1, const float* __restrict__ fB1,
    const float* __restrict__ fW2, const float* __restrict__ fB2)
{
    __shared__ float4 sH[512];   // 256 nodes x 8 f32
    __shared__ float4 sP[256];   // 256 nodes x (3+pad) f32
    __shared__ float4 sE[512];   // edge activations ea
    __shared__ float4 sD[256];   // edge dp
    const int t = threadIdx.x;
    const int g0 = blockIdx.x * TOUT;
    const int g = g0 - 8 + t;

    float4 z4 = make_float4(0.f, 0.f, 0.f, 0.f);
    float4 ha = z4, hb = z4, pa = z4;
    if (g >= 0 && g < NTOT) {
        const float4* hp = (const float4*)(h0 + (long)g * 8);
        ha = hp[0];
        hb = hp[1];
        pa = ((const float4*)pos0)[g];
    }
    sH[t * 2] = ha;
    sH[t * 2 + 1] = hb;
    sP[t] = pa;
    __syncthreads();

    const int tp = (t < 255) ? (t + 1) : t;
    const int tm = (t > 0) ? (t - 1) : t;
    float hn[8] = {0, 0, 0, 0, 0, 0, 0, 0};

    #pragma unroll 1
    for (int li = 0; li < NLAY; ++li) {
        // ---- edge phase: edge (g, g+1) handled by thread t ----
        float hl[8], hr[8];
        {
            float4 a = sH[t * 2], b = sH[t * 2 + 1];
            hl[0] = a.x; hl[1] = a.y; hl[2] = a.z; hl[3] = a.w;
            hl[4] = b.x; hl[5] = b.y; hl[6] = b.z; hl[7] = b.w;
            float4 c = sH[tp * 2], d = sH[tp * 2 + 1];
            hr[0] = c.x; hr[1] = c.y; hr[2] = c.z; hr[3] = c.w;
            hr[4] = d.x; hr[5] = d.y; hr[6] = d.z; hr[7] = d.w;
        }
        float4 plv = sP[t], prv = sP[tp];
        float r0 = prv.x - plv.x, r1 = prv.y - plv.y, r2 = prv.z - plv.z;
        float dist = sqrtf(r0 * r0 + r1 * r1 + r2 * r2);

        const float* wE1 = ceW1 + li * 136;
        const float* bE1 = ceB1 + li * 8;
        const float* wE2 = ceW2 + li * 64;
        const float* bE2 = ceB2 + li * 8;
        const float* wP1 = cpW1 + li * 64;
        const float* bP1 = cpB1 + li * 8;
        const float* wP2 = cpW2 + li * 24;
        const float* wN1 = cnW1 + li * 128;
        const float* bN1 = cnB1 + li * 8;
        const float* wN2 = cnW2 + li * 64;
        const float* bN2 = cnB2 + li * 8;

        float t1[8];
        #pragma unroll
        for (int j = 0; j < 8; ++j) {
            float a = bE1[j];
            #pragma unroll
            for (int r = 0; r < 8; ++r) a += hl[r] * wE1[r * 8 + j];
            #pragma unroll
            for (int r = 0; r < 8; ++r) a += hr[r] * wE1[64 + r * 8 + j];
            a += dist * wE1[128 + j];
            t1[j] = silu_f(a);
        }
        float ea[8];
        #pragma unroll
        for (int j = 0; j < 8; ++j) {
            float a = bE2[j];
            #pragma unroll
            for (int r = 0; r < 8; ++r) a += t1[r] * wE2[r * 8 + j];
            ea[j] = a;
        }
        float q[8];
        #pragma unroll
        for (int j = 0; j < 8; ++j) {
            float a = bP1[j];
            #pragma unroll
            for (int r = 0; r < 8; ++r) a += ea[r] * wP1[r * 8 + j];
            q[j] = silu_f(a);
        }
        float dp0 = 0.f, dp1 = 0.f, dp2 = 0.f;
        #pragma unroll
        for (int r = 0; r < 8; ++r) {
            dp0 += q[r] * wP2[r * 3 + 0];
            dp1 += q[r] * wP2[r * 3 + 1];
            dp2 += q[r] * wP2[r * 3 + 2];
        }
        sE[t * 2] = make_float4(ea[0], ea[1], ea[2], ea[3]);
        sE[t * 2 + 1] = make_float4(ea[4], ea[5], ea[6], ea[7]);
        sD[t] = make_float4(dp0, dp1, dp2, 0.f);
        __syncthreads();

        // ---- node phase ----
        float nu[8] = {0, 0, 0, 0, 0, 0, 0, 0};
        float pu0 = 0.f, pu1 = 0.f, pu2 = 0.f;
        if (g < NTOT - 1) {   // own (right) edge contributes
            #pragma unroll
            for (int j = 0; j < 8; ++j) nu[j] += ea[j];
            pu0 += dp0; pu1 += dp1; pu2 += dp2;
        }
        if (g > 0) {          // left edge contributes
            float4 a = sE[tm * 2], b = sE[tm * 2 + 1];
            nu[0] += a.x; nu[1] += a.y; nu[2] += a.z; nu[3] += a.w;
            nu[4] += b.x; nu[5] += b.y; nu[6] += b.z; nu[7] += b.w;
            float4 dl = sD[tm];
            pu0 -= dl.x; pu1 -= dl.y; pu2 -= dl.z;
        }
        float u[8];
        #pragma unroll
        for (int j = 0; j < 8; ++j) {
            float a = bN1[j];
            #pragma unroll
            for (int r = 0; r < 8; ++r) a += hl[r] * wN1[r * 8 + j];
            #pragma unroll
            for (int r = 0; r < 8; ++r) a += nu[r] * wN1[64 + r * 8 + j];
            u[j] = silu_f(a);
        }
        #pragma unroll
        for (int j = 0; j < 8; ++j) {
            float a = bN2[j];
            #pragma unroll
            for (int r = 0; r < 8; ++r) a += u[r] * wN2[r * 8 + j];
            hn[j] = a;
        }
        float pn0 = plv.x + 0.1f * pu0;
        float pn1 = plv.y + 0.1f * pu1;
        float pn2 = plv.z + 0.1f * pu2;

        if (li == 3) {  // mid latent: tol then froml (pointwise per node)
            float a8[8];
            #pragma unroll
            for (int j = 0; j < 8; ++j) {
                float a = tB1[j];
                #pragma unroll
                for (int r = 0; r < 8; ++r) a += hn[r] * tW1[r * 8 + j];
                a8[j] = silu_f(a);
            }
            float zz[8];
            #pragma unroll
            for (int j = 0; j < 8; ++j) {
                float a = tB2[j];
                #pragma unroll
                for (int r = 0; r < 8; ++r) a += a8[r] * tW2[r * 8 + j];
                zz[j] = a;
            }
            float b8[8];
            #pragma unroll
            for (int j = 0; j < 8; ++j) {
                float a = fB1[j];
                #pragma unroll
                for (int r = 0; r < 8; ++r) a += zz[r] * fW1[r * 8 + j];
                b8[j] = silu_f(a);
            }
            #pragma unroll
            for (int j = 0; j < 8; ++j) {
                float a = fB2[j];
                #pragma unroll
                for (int r = 0; r < 8; ++r) a += b8[r] * fW2[r * 8 + j];
                hn[j] = a;
            }
        }

        // shrinking validity window: only these stores are exact
        const int winLo2 = max(0, g0 - 7 + li);
        const int winHi2 = min(NTOT, g0 + 247 - li);
        if (g >= winLo2 && g < winHi2) {
            sH[t * 2] = make_float4(hn[0], hn[1], hn[2], hn[3]);
            sH[t * 2 + 1] = make_float4(hn[4], hn[5], hn[6], hn[7]);
            sP[t] = make_float4(pn0, pn1, pn2, 0.f);
        }
        __syncthreads();
    }

    if (t >= 8 && t < 8 + TOUT && g < NTOT) {
        float4* hd = (float4*)(hfin + (long)g * 8);
        hd[0] = make_float4(hn[0], hn[1], hn[2], hn[3]);
        hd[1] = make_float4(hn[4], hn[5], hn[6], hn[7]);
    }
}

// ---------------- Kernel 3: decode (h -> pos_out, mask_out) ---------------
// 128 nodes/block, 256 threads. h and t1 in LDS, then output-stationary loops
// over the 111- and 37-wide outputs -> fully coalesced stores.
__global__ __launch_bounds__(256) void k_decode(
    const float* __restrict__ hfin,
    const float* __restrict__ dW1, const float* __restrict__ dB1,
    const float* __restrict__ dW2, const float* __restrict__ dB2,
    const float* __restrict__ mW, const float* __restrict__ mB,
    float* __restrict__ out)
{
    __shared__ alignas(16) float sh[128 * 8];
    __shared__ float st1[128 * 16];
    const int tid = threadIdx.x;
    const long nb = (long)blockIdx.x * 128;

    ((float4*)sh)[tid] = ((const float4*)(hfin + nb * 8))[tid];
    __syncthreads();

    {   // t1 = silu(h @ posdec_W1 + b1): 2 threads per node, 8 cols each
        const int n = tid >> 1;
        const int c0 = (tid & 1) * 8;
        const float* hr = sh + n * 8;
        #pragma unroll
        for (int jj = 0; jj < 8; ++jj) {
            int j = c0 + jj;
            float a = dB1[j];
            #pragma unroll
            for (int r = 0; r < 8; ++r) a += hr[r] * dW1[r * 16 + j];
            st1[n * 16 + j] = silu_f(a);
        }
    }
    __syncthreads();

    // pos_out: 128 * 111 contiguous floats per block
    const long posBase = nb * 111;
    #pragma unroll 1
    for (int o = tid; o < 128 * 111; o += 256) {
        unsigned n = (unsigned)o / 111u;
        unsigned j = (unsigned)o - n * 111u;
        float a = dB2[j];
        const float* t1r = st1 + n * 16;
        #pragma unroll
        for (int r = 0; r < 16; ++r) a += t1r[r] * dW2[r * 111 + j];
        out[posBase + o] = a;
    }
    // mask_out: offset NTOT*111, 128 * 37 contiguous floats per block
    const long mBase = (long)NTOT * 111 + nb * 37;
    #pragma unroll 1
    for (int o = tid; o < 128 * 37; o += 256) {
        unsigned n = (unsigned)o / 37u;
        unsigned j = (unsigned)o - n * 37u;
        float a = mB[j];
        const float* hr = sh + n * 8;
        #pragma unroll
        for (int r = 0; r < 8; ++r) a += hr[r] * mW[r * 37 + j];
        out[mBase + o] = a;
    }
}

extern "C" void kernel_launch(void* const* d_in, const int* in_sizes, int n_in,
                              void* d_out, int out_size, void* d_ws, size_t ws_size,
                              hipStream_t stream) {
    const float* ap     = (const float*)d_in[0];
    const float* amask  = (const float*)d_in[1];
    const float* embW   = (const float*)d_in[2];
    const float* embB   = (const float*)d_in[3];
    const float* peW1   = (const float*)d_in[4];
    const float* peB1   = (const float*)d_in[5];
    const float* peW2   = (const float*)d_in[6];
    const float* peB2   = (const float*)d_in[7];
    const float* ceW1   = (const float*)d_in[8];
    const float* ceB1   = (const float*)d_in[9];
    const float* ceW2   = (const float*)d_in[10];
    const float* ceB2   = (const float*)d_in[11];
    const float* cpW1   = (const float*)d_in[12];
    const float* cpB1   = (const float*)d_in[13];
    const float* cpW2   = (const float*)d_in[14];
    const float* cnW1   = (const float*)d_in[15];
    const float* cnB1   = (const float*)d_in[16];
    const float* cnW2   = (const float*)d_in[17];
    const float* cnB2   = (const float*)d_in[18];
    const float* tW1    = (const float*)d_in[19];
    const float* tB1    = (const float*)d_in[20];
    const float* tW2    = (const float*)d_in[21];
    const float* tB2    = (const float*)d_in[22];
    const float* fW1    = (const float*)d_in[23];
    const float* fB1    = (const float*)d_in[24];
    const float* fW2    = (const float*)d_in[25];
    const float* fB2    = (const float*)d_in[26];
    const float* dW1    = (const float*)d_in[27];
    const float* dB1    = (const float*)d_in[28];
    const float* dW2    = (const float*)d_in[29];
    const float* dB2    = (const float*)d_in[30];
    const float* mW     = (const float*)d_in[31];
    const float* mB     = (const float*)d_in[32];

    // workspace layout (needs 20 MB): h0 [N*8] | pos0 [N*4] | hfin [N*8]
    float* h0   = (float*)d_ws;
    float* pos0 = h0 + (size_t)NTOT * 8;
    float* hfin = pos0 + (size_t)NTOT * 4;
    float* out  = (float*)d_out;

    k_encode<<<NTOT / 64, 256, 0, stream>>>(ap, amask, embW, embB,
                                            peW1, peB1, peW2, peB2, h0, pos0);
    k_stack<<<(NTOT + TOUT - 1) / TOUT, 256, 0, stream>>>(
        h0, pos0, hfin,
        ceW1, ceB1, ceW2, ceB2, cpW1, cpB1, cpW2,
        cnW1, cnB1, cnW2, cnB2,
        tW1, tB1, tW2, tB2, fW1, fB1, fW2, fB2);
    k_decode<<<NTOT / 128, 256, 0, stream>>>(hfin, dW1, dB1, dW2, dB2, mW, mB, out);
}

// Round 2
// 433.692 us; speedup vs baseline: 1.2032x; 1.2032x over previous
//
#include <hip/hip_runtime.h>

#define NTOT 262144   // B*L
#define NLAY 8
#define TOUT 240      // output nodes per block in k_stack (256 LDS nodes - 2*8 halo)

__device__ __forceinline__ float silu_f(float x) {
    return x * (1.0f / (1.0f + __expf(-x)));
}

// ---------------- Kernel 1: encode  (mask/pos -> h0, pos0) ----------------
// 64 nodes per block, 256 threads, 4 threads per node (atoms split 10/10/10/7),
// butterfly shuffle-reduce the partials, then all lanes compute the tiny MLP
// (uniform weights -> scalar loads) and split the stores across the quad.
__global__ __launch_bounds__(256) void k_encode(
    const float* __restrict__ ap, const float* __restrict__ amask,
    const float* __restrict__ embW, const float* __restrict__ embB,
    const float* __restrict__ peW1, const float* __restrict__ peB1,
    const float* __restrict__ peW2, const float* __restrict__ peB2,
    float* __restrict__ h0, float* __restrict__ pos0)
{
    __shared__ alignas(16) float sM[64 * 37];
    __shared__ alignas(16) float sA[64 * 111];
    __shared__ alignas(16) float sW[37 * 8];     // embW staged (296 floats)
    const int tid = threadIdx.x;
    const long nb = (long)blockIdx.x * 64;

    if (tid < 74) ((float4*)sW)[tid] = ((const float4*)embW)[tid];
    const float4* gm = (const float4*)(amask + nb * 37);
    float4* sm4 = (float4*)sM;
    #pragma unroll 1
    for (int i = tid; i < 64 * 37 / 4; i += 256) sm4[i] = gm[i];
    const float4* ga = (const float4*)(ap + nb * 111);
    float4* sa4 = (float4*)sA;
    #pragma unroll 1
    for (int i = tid; i < 64 * 111 / 4; i += 256) sa4[i] = ga[i];
    __syncthreads();

    const int n = tid >> 2;          // node within block
    const int p = tid & 3;           // quad lane
    const int k0 = p * 10;
    const int k1 = (p == 3) ? 37 : k0 + 10;

    const float* mrow = sM + n * 37;
    const float* arow = sA + n * 111;
    float hacc[8] = {0, 0, 0, 0, 0, 0, 0, 0};
    float ps0 = 0.f, ps1 = 0.f, ps2 = 0.f, msum = 0.f;
    #pragma unroll 1
    for (int k = k0; k < k1; ++k) {
        float mv = mrow[k];
        msum += mv;
        const float4* wr = (const float4*)(sW + k * 8);
        float4 w0 = wr[0], w1 = wr[1];
        hacc[0] += mv * w0.x; hacc[1] += mv * w0.y;
        hacc[2] += mv * w0.z; hacc[3] += mv * w0.w;
        hacc[4] += mv * w1.x; hacc[5] += mv * w1.y;
        hacc[6] += mv * w1.z; hacc[7] += mv * w1.w;
        ps0 += mv * arow[k * 3 + 0];
        ps1 += mv * arow[k * 3 + 1];
        ps2 += mv * arow[k * 3 + 2];
    }
    // butterfly reduce across the quad (12 values)
    #pragma unroll
    for (int m = 1; m <= 2; m <<= 1) {
        msum += __shfl_xor(msum, m);
        ps0 += __shfl_xor(ps0, m);
        ps1 += __shfl_xor(ps1, m);
        ps2 += __shfl_xor(ps2, m);
        #pragma unroll
        for (int j = 0; j < 8; ++j) hacc[j] += __shfl_xor(hacc[j], m);
    }

    float inv = 1.0f / (msum + 1e-8f);
    float mp0 = ps0 * inv, mp1 = ps1 * inv, mp2 = ps2 * inv;
    float q[8];
    #pragma unroll
    for (int j = 0; j < 8; ++j) {
        float a = peB1[j];
        a += mp0 * peW1[0 * 8 + j];
        a += mp1 * peW1[1 * 8 + j];
        a += mp2 * peW1[2 * 8 + j];
        q[j] = silu_f(a);
    }
    #pragma unroll
    for (int j = 0; j < 8; ++j) {
        float a = peB2[j] + embB[j];
        #pragma unroll
        for (int r = 0; r < 8; ++r) a += q[r] * peW2[r * 8 + j];
        hacc[j] += a;
    }
    const long g = nb + n;
    if (p == 0) ((float4*)(h0 + g * 8))[0] = make_float4(hacc[0], hacc[1], hacc[2], hacc[3]);
    if (p == 1) ((float4*)(h0 + g * 8))[1] = make_float4(hacc[4], hacc[5], hacc[6], hacc[7]);
    if (p == 2) ((float4*)pos0)[g] = make_float4(mp0, mp1, mp2, 0.f);
}

// ---------------- Kernel 2: fused 8-layer SE3 stack + mid latent ----------
// (unchanged from round 1 — counters will become visible this round)
__global__ __launch_bounds__(256) void k_stack(
    const float* __restrict__ h0, const float* __restrict__ pos0,
    float* __restrict__ hfin,
    const float* __restrict__ ceW1, const float* __restrict__ ceB1,
    const float* __restrict__ ceW2, const float* __restrict__ ceB2,
    const float* __restrict__ cpW1, const float* __restrict__ cpB1,
    const float* __restrict__ cpW2,
    const float* __restrict__ cnW1, const float* __restrict__ cnB1,
    const float* __restrict__ cnW2, const float* __restrict__ cnB2,
    const float* __restrict__ tW1, const float* __restrict__ tB1,
    const float* __restrict__ tW2, const float* __restrict__ tB2,
    const float* __restrict__ fW1, const float* __restrict__ fB1,
    const float* __restrict__ fW2, const float* __restrict__ fB2)
{
    __shared__ float4 sH[512];   // 256 nodes x 8 f32
    __shared__ float4 sP[256];   // 256 nodes x (3+pad) f32
    __shared__ float4 sE[512];   // edge activations ea
    __shared__ float4 sD[256];   // edge dp
    const int t = threadIdx.x;
    const int g0 = blockIdx.x * TOUT;
    const int g = g0 - 8 + t;

    float4 z4 = make_float4(0.f, 0.f, 0.f, 0.f);
    float4 ha = z4, hb = z4, pa = z4;
    if (g >= 0 && g < NTOT) {
        const float4* hp = (const float4*)(h0 + (long)g * 8);
        ha = hp[0];
        hb = hp[1];
        pa = ((const float4*)pos0)[g];
    }
    sH[t * 2] = ha;
    sH[t * 2 + 1] = hb;
    sP[t] = pa;
    __syncthreads();

    const int tp = (t < 255) ? (t + 1) : t;
    const int tm = (t > 0) ? (t - 1) : t;
    float hn[8] = {0, 0, 0, 0, 0, 0, 0, 0};

    #pragma unroll 1
    for (int li = 0; li < NLAY; ++li) {
        float hl[8], hr[8];
        {
            float4 a = sH[t * 2], b = sH[t * 2 + 1];
            hl[0] = a.x; hl[1] = a.y; hl[2] = a.z; hl[3] = a.w;
            hl[4] = b.x; hl[5] = b.y; hl[6] = b.z; hl[7] = b.w;
            float4 c = sH[tp * 2], d = sH[tp * 2 + 1];
            hr[0] = c.x; hr[1] = c.y; hr[2] = c.z; hr[3] = c.w;
            hr[4] = d.x; hr[5] = d.y; hr[6] = d.z; hr[7] = d.w;
        }
        float4 plv = sP[t], prv = sP[tp];
        float r0 = prv.x - plv.x, r1 = prv.y - plv.y, r2 = prv.z - plv.z;
        float dist = sqrtf(r0 * r0 + r1 * r1 + r2 * r2);

        const float* wE1 = ceW1 + li * 136;
        const float* bE1 = ceB1 + li * 8;
        const float* wE2 = ceW2 + li * 64;
        const float* bE2 = ceB2 + li * 8;
        const float* wP1 = cpW1 + li * 64;
        const float* bP1 = cpB1 + li * 8;
        const float* wP2 = cpW2 + li * 24;
        const float* wN1 = cnW1 + li * 128;
        const float* bN1 = cnB1 + li * 8;
        const float* wN2 = cnW2 + li * 64;
        const float* bN2 = cnB2 + li * 8;

        float t1[8];
        #pragma unroll
        for (int j = 0; j < 8; ++j) {
            float a = bE1[j];
            #pragma unroll
            for (int r = 0; r < 8; ++r) a += hl[r] * wE1[r * 8 + j];
            #pragma unroll
            for (int r = 0; r < 8; ++r) a += hr[r] * wE1[64 + r * 8 + j];
            a += dist * wE1[128 + j];
            t1[j] = silu_f(a);
        }
        float ea[8];
        #pragma unroll
        for (int j = 0; j < 8; ++j) {
            float a = bE2[j];
            #pragma unroll
            for (int r = 0; r < 8; ++r) a += t1[r] * wE2[r * 8 + j];
            ea[j] = a;
        }
        float q[8];
        #pragma unroll
        for (int j = 0; j < 8; ++j) {
            float a = bP1[j];
            #pragma unroll
            for (int r = 0; r < 8; ++r) a += ea[r] * wP1[r * 8 + j];
            q[j] = silu_f(a);
        }
        float dp0 = 0.f, dp1 = 0.f, dp2 = 0.f;
        #pragma unroll
        for (int r = 0; r < 8; ++r) {
            dp0 += q[r] * wP2[r * 3 + 0];
            dp1 += q[r] * wP2[r * 3 + 1];
            dp2 += q[r] * wP2[r * 3 + 2];
        }
        sE[t * 2] = make_float4(ea[0], ea[1], ea[2], ea[3]);
        sE[t * 2 + 1] = make_float4(ea[4], ea[5], ea[6], ea[7]);
        sD[t] = make_float4(dp0, dp1, dp2, 0.f);
        __syncthreads();

        float nu[8] = {0, 0, 0, 0, 0, 0, 0, 0};
        float pu0 = 0.f, pu1 = 0.f, pu2 = 0.f;
        if (g < NTOT - 1) {
            #pragma unroll
            for (int j = 0; j < 8; ++j) nu[j] += ea[j];
            pu0 += dp0; pu1 += dp1; pu2 += dp2;
        }
        if (g > 0) {
            float4 a = sE[tm * 2], b = sE[tm * 2 + 1];
            nu[0] += a.x; nu[1] += a.y; nu[2] += a.z; nu[3] += a.w;
            nu[4] += b.x; nu[5] += b.y; nu[6] += b.z; nu[7] += b.w;
            float4 dl = sD[tm];
            pu0 -= dl.x; pu1 -= dl.y; pu2 -= dl.z;
        }
        float u[8];
        #pragma unroll
        for (int j = 0; j < 8; ++j) {
            float a = bN1[j];
            #pragma unroll
            for (int r = 0; r < 8; ++r) a += hl[r] * wN1[r * 8 + j];
            #pragma unroll
            for (int r = 0; r < 8; ++r) a += nu[r] * wN1[64 + r * 8 + j];
            u[j] = silu_f(a);
        }
        #pragma unroll
        for (int j = 0; j < 8; ++j) {
            float a = bN2[j];
            #pragma unroll
            for (int r = 0; r < 8; ++r) a += u[r] * wN2[r * 8 + j];
            hn[j] = a;
        }
        float pn0 = plv.x + 0.1f * pu0;
        float pn1 = plv.y + 0.1f * pu1;
        float pn2 = plv.z + 0.1f * pu2;

        if (li == 3) {
            float a8[8];
            #pragma unroll
            for (int j = 0; j < 8; ++j) {
                float a = tB1[j];
                #pragma unroll
                for (int r = 0; r < 8; ++r) a += hn[r] * tW1[r * 8 + j];
                a8[j] = silu_f(a);
            }
            float zz[8];
            #pragma unroll
            for (int j = 0; j < 8; ++j) {
                float a = tB2[j];
                #pragma unroll
                for (int r = 0; r < 8; ++r) a += a8[r] * tW2[r * 8 + j];
                zz[j] = a;
            }
            float b8[8];
            #pragma unroll
            for (int j = 0; j < 8; ++j) {
                float a = fB1[j];
                #pragma unroll
                for (int r = 0; r < 8; ++r) a += zz[r] * fW1[r * 8 + j];
                b8[j] = silu_f(a);
            }
            #pragma unroll
            for (int j = 0; j < 8; ++j) {
                float a = fB2[j];
                #pragma unroll
                for (int r = 0; r < 8; ++r) a += b8[r] * fW2[r * 8 + j];
                hn[j] = a;
            }
        }

        const int winLo2 = max(0, g0 - 7 + li);
        const int winHi2 = min(NTOT, g0 + 247 - li);
        if (g >= winLo2 && g < winHi2) {
            sH[t * 2] = make_float4(hn[0], hn[1], hn[2], hn[3]);
            sH[t * 2 + 1] = make_float4(hn[4], hn[5], hn[6], hn[7]);
            sP[t] = make_float4(pn0, pn1, pn2, 0.f);
        }
        __syncthreads();
    }

    if (t >= 8 && t < 8 + TOUT && g < NTOT) {
        float4* hd = (float4*)(hfin + (long)g * 8);
        hd[0] = make_float4(hn[0], hn[1], hn[2], hn[3]);
        hd[1] = make_float4(hn[4], hn[5], hn[6], hn[7]);
    }
}

// ---------------- Kernel 3: decode (h -> pos_out, mask_out) ---------------
// 128 nodes/block, 256 threads. Column-stationary: thread owns output column j,
// weights live in registers, t1/h read from LDS via broadcast ds_read_b128.
__global__ __launch_bounds__(256) void k_decode(
    const float* __restrict__ hfin,
    const float* __restrict__ dW1, const float* __restrict__ dB1,
    const float* __restrict__ dW2, const float* __restrict__ dB2,
    const float* __restrict__ mW, const float* __restrict__ mB,
    float* __restrict__ out)
{
    __shared__ alignas(16) float sh[128 * 8];
    __shared__ alignas(16) float st1[128 * 16];
    const int tid = threadIdx.x;
    const long nb = (long)blockIdx.x * 128;

    ((float4*)sh)[tid] = ((const float4*)(hfin + nb * 8))[tid];
    __syncthreads();

    {   // t1 = silu(h @ posdec_W1 + b1): 2 threads per node, 8 cols each
        const int n = tid >> 1;
        const int c0 = (tid & 1) * 8;
        const float4* h4 = (const float4*)(sh + n * 8);
        float4 h0v = h4[0], h1v = h4[1];
        float hr[8] = {h0v.x, h0v.y, h0v.z, h0v.w, h1v.x, h1v.y, h1v.z, h1v.w};
        #pragma unroll
        for (int jj = 0; jj < 8; ++jj) {
            int j = c0 + jj;
            float a = dB1[j];
            #pragma unroll
            for (int r = 0; r < 8; ++r) a += hr[r] * dW1[r * 16 + j];
            st1[n * 16 + j] = silu_f(a);
        }
    }
    __syncthreads();

    if (tid < 222) {
        // ---- pos_out: column-stationary, 2 node-phases ----
        const int half = (tid >= 111) ? 1 : 0;
        const int j = tid - half * 111;
        float w[16];
        #pragma unroll
        for (int r = 0; r < 16; ++r) w[r] = dW2[r * 111 + j];
        const float bj = dB2[j];
        float* op = out + nb * 111 + j;
        #pragma unroll 2
        for (int n = half; n < 128; n += 2) {
            const float4* t4 = (const float4*)(st1 + n * 16);
            float4 a0 = t4[0], a1 = t4[1], a2 = t4[2], a3 = t4[3];
            float acc = bj;
            acc += a0.x * w[0] + a0.y * w[1] + a0.z * w[2] + a0.w * w[3];
            acc += a1.x * w[4] + a1.y * w[5] + a1.z * w[6] + a1.w * w[7];
            acc += a2.x * w[8] + a2.y * w[9] + a2.z * w[10] + a2.w * w[11];
            acc += a3.x * w[12] + a3.y * w[13] + a3.z * w[14] + a3.w * w[15];
            op[n * 111] = acc;
        }
        // ---- mask_out: column-stationary, 6 node-phases ----
        const int g6 = tid / 37;      // 0..5
        const int j2 = tid - g6 * 37;
        float wm[8];
        #pragma unroll
        for (int r = 0; r < 8; ++r) wm[r] = mW[r * 37 + j2];
        const float bm = mB[j2];
        float* omp_ = out + (long)NTOT * 111 + nb * 37 + j2;
        #pragma unroll 1
        for (int n = g6; n < 128; n += 6) {
            const float4* h4 = (const float4*)(sh + n * 8);
            float4 h0v = h4[0], h1v = h4[1];
            float acc = bm;
            acc += h0v.x * wm[0] + h0v.y * wm[1] + h0v.z * wm[2] + h0v.w * wm[3];
            acc += h1v.x * wm[4] + h1v.y * wm[5] + h1v.z * wm[6] + h1v.w * wm[7];
            omp_[n * 37] = acc;
        }
    }
}

extern "C" void kernel_launch(void* const* d_in, const int* in_sizes, int n_in,
                              void* d_out, int out_size, void* d_ws, size_t ws_size,
                              hipStream_t stream) {
    const float* ap     = (const float*)d_in[0];
    const float* amask  = (const float*)d_in[1];
    const float* embW   = (const float*)d_in[2];
    const float* embB   = (const float*)d_in[3];
    const float* peW1   = (const float*)d_in[4];
    const float* peB1   = (const float*)d_in[5];
    const float* peW2   = (const float*)d_in[6];
    const float* peB2   = (const float*)d_in[7];
    const float* ceW1   = (const float*)d_in[8];
    const float* ceB1   = (const float*)d_in[9];
    const float* ceW2   = (const float*)d_in[10];
    const float* ceB2   = (const float*)d_in[11];
    const float* cpW1   = (const float*)d_in[12];
    const float* cpB1   = (const float*)d_in[13];
    const float* cpW2   = (const float*)d_in[14];
    const float* cnW1   = (const float*)d_in[15];
    const float* cnB1   = (const float*)d_in[16];
    const float* cnW2   = (const float*)d_in[17];
    const float* cnB2   = (const float*)d_in[18];
    const float* tW1    = (const float*)d_in[19];
    const float* tB1    = (const float*)d_in[20];
    const float* tW2    = (const float*)d_in[21];
    const float* tB2    = (const float*)d_in[22];
    const float* fW1    = (const float*)d_in[23];
    const float* fB1    = (const float*)d_in[24];
    const float* fW2    = (const float*)d_in[25];
    const float* fB2    = (const float*)d_in[26];
    const float* dW1    = (const float*)d_in[27];
    const float* dB1    = (const float*)d_in[28];
    const float* dW2    = (const float*)d_in[29];
    const float* dB2    = (const float*)d_in[30];
    const float* mW     = (const float*)d_in[31];
    const float* mB     = (const float*)d_in[32];

    float* h0   = (float*)d_ws;
    float* pos0 = h0 + (size_t)NTOT * 8;
    float* hfin = pos0 + (size_t)NTOT * 4;
    float* out  = (float*)d_out;

    k_encode<<<NTOT / 64, 256, 0, stream>>>(ap, amask, embW, embB,
                                            peW1, peB1, peW2, peB2, h0, pos0);
    k_stack<<<(NTOT + TOUT - 1) / TOUT, 256, 0, stream>>>(
        h0, pos0, hfin,
        ceW1, ceB1, ceW2, ceB2, cpW1, cpB1, cpW2,
        cnW1, cnB1, cnW2, cnB2,
        tW1, tB1, tW2, tB2, fW1, fB1, fW2, fB2);
    k_decode<<<NTOT / 128, 256, 0, stream>>>(hfin, dW1, dB1, dW2, dB2, mW, mB, out);
}